// Round 2
// baseline (67.669 us; speedup 1.0000x reference)
//
#include <hip/hip_runtime.h>
#include <math.h>

// MeshfreeKAN2D forward.
// x:[B,2] nodes:[N,2] W1a:[16,7] W1b:[16,7] W2:[1,112] w:[N,1] -> out:[B,1]
// B=1024, N=2048 in this instance.
//
// Structure: one block per query row.
//   Phase 1 (branchless): distances^2 for all N nodes -> LDS; compact hit
//            indices (dist <= 0.1) into an LDS list via LDS atomics.
//   Phase 2: KAN eval only over compacted hits (~64/row) at full lane util.
//   Hat-basis sums evaluated as 2-point lerps (<=2 nonzero hats).
//   Orphan rows (no support) fall back to exact serial 8-NN on thread 0 —
//   probability ~e^-64, but must match lax.top_k semantics (ties -> low idx).

constexpr int NB    = 7;
constexpr int NH    = 16;
constexpr int BLOCK = 256;
constexpr int NMAX  = 2048;

__global__ __launch_bounds__(BLOCK) void meshfree_kan_fwd(
    const float* __restrict__ x,
    const float* __restrict__ nodes,
    const float* __restrict__ W1a,
    const float* __restrict__ W1b,
    const float* __restrict__ W2,
    const float* __restrict__ w,
    float* __restrict__ out,
    int N)
{
    __shared__ float sW1a[NH * NB];
    __shared__ float sW1b[NH * NB];
    __shared__ float sW2 [NH * NB];
    __shared__ float sd2 [NMAX];      // squared distances (for orphan fallback)
    __shared__ int   shidx[NMAX];     // compacted hit indices
    __shared__ int   hcount;
    __shared__ float sred[2][BLOCK / 64];

    const int tid = threadIdx.x;
    const int b   = blockIdx.x;

    for (int i = tid; i < NH * NB; i += BLOCK) {
        sW1a[i] = W1a[i];
        sW1b[i] = W1b[i];
        sW2[i]  = W2[i];
    }
    if (tid == 0) hcount = 0;
    const float xb0 = x[2 * b + 0];
    const float xb1 = x[2 * b + 1];
    __syncthreads();

    // ---------- phase 1: distances + hit compaction ----------
    for (int base = 0; base < N; base += BLOCK) {
        const int n = base + tid;
        if (n < N) {
            const float2 nd = ((const float2*)nodes)[n];
            const float dx = xb0 - nd.x;
            const float dy = xb1 - nd.y;
            const float d2 = dx * dx + dy * dy;
            sd2[n] = d2;
            // dist <= 0.1  <=>  d2 <= 0.01 (tiny inclusive fuzz: boundary
            // terms carry window ~(1-q)^3 ~ 1e-21, negligible either way)
            if (d2 <= 0.0100000019f) {
                const int p = atomicAdd(&hcount, 1);
                shidx[p] = n;
            }
        }
    }
    __syncthreads();
    const int H = hcount;

    // ---------- phase 2: KAN eval over compacted hits ----------
    float sum_phi  = 0.0f;
    float sum_phiw = 0.0f;

    for (int k = tid; k < H; k += BLOCK) {
        const int n = shidx[k];
        const float2 nd = ((const float2*)nodes)[n];
        const float dx = xb0 - nd.x;
        const float dy = xb1 - nd.y;
        const float dist = sqrtf(dx * dx + dy * dy);
        const float q  = dist * 10.0f;   // dist / 0.1
        const float kx = dx * 10.0f;
        const float ky = dy * 10.0f;

        // input-layer basis: 2-point lerp; |kx|,|ky| <= 1+ulp -> j in [0,5]
        const float u0 = (kx + 1.5f) * 2.0f;
        const float f0 = floorf(u0);
        const int   j0 = (int)f0;
        const float t0 = u0 - f0;
        const float u1 = (ky + 1.5f) * 2.0f;
        const float f1 = floorf(u1);
        const int   j1 = (int)f1;
        const float t1 = u1 - f1;

        float acc = 0.0f;
        #pragma unroll
        for (int h = 0; h < NH; ++h) {
            const float hid =
                sW1a[h * NB + j0]     * (1.0f - t0) +
                sW1a[h * NB + j0 + 1] * t0 +
                sW1b[h * NB + j1]     * (1.0f - t1) +
                sW1b[h * NB + j1 + 1] * t1;
            const float uh = (hid + 1.5f) * 2.0f;
            const float fh = floorf(uh);
            const int   jh = (int)fh;
            const float th = uh - fh;
            const float c0 = ((unsigned)jh       <= 6u) ? sW2[h * NB + jh]     : 0.0f;
            const float c1 = ((unsigned)(jh + 1) <= 6u) ? sW2[h * NB + jh + 1] : 0.0f;
            acc += c0 * (1.0f - th) + c1 * th;
        }

        // stable softplus: max(x,0) + log1p(exp(-|x|))
        const float phi_raw = fmaxf(acc, 0.0f) + log1pf(expf(-fabsf(acc)));
        // cubic window (branch boundaries agree with reference at q=0.5,1)
        float wnd;
        if (q <= 0.5f) {
            wnd = 2.0f / 3.0f - 4.0f * q * q + 4.0f * q * q * q;
        } else if (q <= 1.0f) {
            wnd = 4.0f / 3.0f - 4.0f * q + 4.0f * q * q - (4.0f / 3.0f) * q * q * q;
        } else {
            wnd = 0.0f;
        }
        const float phi = phi_raw * wnd;
        sum_phi  += phi;
        sum_phiw += phi * w[n];
    }

    // ---------- block reduction ----------
    float v0 = sum_phi, v1 = sum_phiw;
    #pragma unroll
    for (int off = 32; off > 0; off >>= 1) {
        v0 += __shfl_down(v0, off, 64);
        v1 += __shfl_down(v1, off, 64);
    }
    const int wave = tid >> 6;
    if ((tid & 63) == 0) {
        sred[0][wave] = v0;
        sred[1][wave] = v1;
    }
    __syncthreads();

    if (tid == 0) {
        float ps = 0.0f, pw = 0.0f;
        #pragma unroll
        for (int i = 0; i < BLOCK / 64; ++i) {
            ps += sred[0][i];
            pw += sred[1][i];
        }
        float result;
        if (fabsf(ps) >= 1e-14f) {
            result = pw / (ps + 1e-12f);
        } else {
            // ---- orphan fallback: exact serial 8-NN over d^2 ----
            // (selection monotone under sqrt; strict < -> lowest index on
            //  ties, matching lax.top_k)
            float dsel[8];
            int   isel[8];
            for (int k = 0; k < 8; ++k) {
                float md = INFINITY;
                int   mi = 0;
                for (int n = 0; n < N; ++n) {
                    const float d = sd2[n];
                    if (d < md) { md = d; mi = n; }
                }
                dsel[k] = sqrtf(md);
                isel[k] = mi;
                sd2[mi] = INFINITY;
            }
            float wts[8];
            float s = 0.0f;
            for (int k = 0; k < 8; ++k) {
                wts[k] = expf(-200.0f * dsel[k]);
                s += wts[k];
            }
            float r = 0.0f;
            for (int k = 0; k < 8; ++k)
                r += (wts[k] / (s + 1e-18f)) * w[isel[k]];
            result = r;
        }
        out[b] = result;
    }
}

extern "C" void kernel_launch(void* const* d_in, const int* in_sizes, int n_in,
                              void* d_out, int out_size, void* d_ws, size_t ws_size,
                              hipStream_t stream) {
    const float* x     = (const float*)d_in[0];
    const float* nodes = (const float*)d_in[1];
    const float* W1a   = (const float*)d_in[2];
    const float* W1b   = (const float*)d_in[3];
    const float* W2    = (const float*)d_in[4];
    const float* w     = (const float*)d_in[5];
    float* out = (float*)d_out;

    const int B = in_sizes[0] / 2;
    const int N = in_sizes[1] / 2;

    meshfree_kan_fwd<<<B, BLOCK, 0, stream>>>(x, nodes, W1a, W1b, W2, w, out, N);
}